// Round 3
// baseline (215.155 us; speedup 1.0000x reference)
//
#include <hip/hip_runtime.h>

// Volume rendering (NeRF-style fancy_integration), f32 in/out.
// B=4, R=32768, S=64 -> 131072 rays, 64 samples. Lane i <-> sample i.
//
// Round 3: rounds 1-2 showed VALU 30% / HBM 22% / LDS 0 — latency-bound on
// wave turnover (one tiny wave per ray; setup + load latency >> work).
// Now each wave processes IT=16 contiguous rays with a 2-stage register
// pipeline: next ray's loads are issued before current ray's data is
// consumed, keeping 5 loads in flight across each compute phase.

#define NSAMP 64
#define EPS_W 1e-10f
#define DELTA_INF_V 1e10f
#define IT 16   // rays per wave

// DPP ctrl encodings (gfx9/CDNA classic DPP)
#define DPP_ROW_SHR(n)  (0x110 | (n))
#define DPP_ROW_BCAST15 0x142
#define DPP_ROW_BCAST31 0x143
#define DPP_WAVE_SHL1   0x130   // lane i <- lane i+1
#define DPP_WAVE_SHR1   0x138   // lane i <- lane i-1

template <int CTRL, int RM, int BM>
__device__ __forceinline__ float dpp_mov(float x, float old) {
    return __builtin_bit_cast(float,
        __builtin_amdgcn_update_dpp(
            __builtin_bit_cast(int, old), __builtin_bit_cast(int, x),
            CTRL, RM, BM, false));
}

// Inclusive multiply-scan across 64 lanes (identity 1.0 via `old`).
__device__ __forceinline__ float scan_mul64(float p) {
    p *= dpp_mov<DPP_ROW_SHR(1), 0xf, 0xf>(p, 1.0f);
    p *= dpp_mov<DPP_ROW_SHR(2), 0xf, 0xf>(p, 1.0f);
    p *= dpp_mov<DPP_ROW_SHR(4), 0xf, 0xf>(p, 1.0f);
    p *= dpp_mov<DPP_ROW_SHR(8), 0xf, 0xf>(p, 1.0f);
    p *= dpp_mov<DPP_ROW_BCAST15, 0xa, 0xf>(p, 1.0f);
    p *= dpp_mov<DPP_ROW_BCAST31, 0xc, 0xf>(p, 1.0f);
    return p;
}

// Inclusive add-scan; lane 63 ends with the full 64-lane sum.
__device__ __forceinline__ float scan_add64(float x) {
    x += dpp_mov<DPP_ROW_SHR(1), 0xf, 0xf>(x, 0.0f);
    x += dpp_mov<DPP_ROW_SHR(2), 0xf, 0xf>(x, 0.0f);
    x += dpp_mov<DPP_ROW_SHR(4), 0xf, 0xf>(x, 0.0f);
    x += dpp_mov<DPP_ROW_SHR(8), 0xf, 0xf>(x, 0.0f);
    x += dpp_mov<DPP_ROW_BCAST15, 0xa, 0xf>(x, 0.0f);
    x += dpp_mov<DPP_ROW_BCAST31, 0xc, 0xf>(x, 0.0f);
    return x;
}

__global__ __launch_bounds__(256) void volrend_kernel(
    const float* __restrict__ rgb,      // [n_rays, 64, 3]
    const float* __restrict__ sigma,    // [n_rays, 64]
    const float* __restrict__ z_vals,   // [n_rays, 64]
    float* __restrict__ rgb_out,        // [n_rays, 3]
    float* __restrict__ depth_out,      // [n_rays]
    float* __restrict__ weights_out,    // [n_rays, 64]
    int n_rays)
{
    const int lane = threadIdx.x & 63;
    const int wave = threadIdx.x >> 6;
    const int waves_per_block = blockDim.x >> 6;
    const long long wave_g = (long long)blockIdx.x * waves_per_block + wave;

    long long ray = wave_g * IT;
    if (ray >= n_rays) return;
    const long long ray_end = (ray + IT < n_rays) ? ray + IT : n_rays;

    // ---- prologue: load ray 0 of this chunk ----
    {
        const long long base = ray * NSAMP + lane;
        const float* rp = rgb + base * 3;
        float sg = sigma[base];
        float z  = z_vals[base];
        float cr = rp[0], cg = rp[1], cb = rp[2];

        #pragma unroll 1
        for (;;) {
            // ---- issue next ray's loads BEFORE consuming current data ----
            const long long nray  = ray + 1;
            const long long pbase = ((nray < ray_end) ? nray : ray) * NSAMP + lane;
            const float* prp = rgb + pbase * 3;
            const float n_sg = sigma[pbase];
            const float n_z  = z_vals[pbase];
            const float n_cr = prp[0], n_cg = prp[1], n_cb = prp[2];

            // ---- compute current ray ----
            const float z_next = dpp_mov<DPP_WAVE_SHL1, 0xf, 0xf>(z, 0.0f);
            const float delta  = (lane == NSAMP - 1) ? DELTA_INF_V : (z_next - z);
            const float alpha  = 1.0f - __expf(-delta * fmaxf(sg, 0.0f));

            const float p = scan_mul64(1.0f - alpha + EPS_W);
            const float T = dpp_mov<DPP_WAVE_SHR1, 0xf, 0xf>(p, 1.0f);
            const float w = alpha * T;

            weights_out[ray * NSAMP + lane] = w;

            const float sr  = scan_add64(w * cr);
            const float sg2 = scan_add64(w * cg);
            const float sb  = scan_add64(w * cb);
            const float sd  = scan_add64(w * z);

            if (lane == NSAMP - 1) {
                rgb_out[ray * 3 + 0] = sr;
                rgb_out[ray * 3 + 1] = sg2;
                rgb_out[ray * 3 + 2] = sb;
                depth_out[ray] = sd;
            }

            if (nray >= ray_end) break;
            ray = nray;
            sg = n_sg; z = n_z; cr = n_cr; cg = n_cg; cb = n_cb;
        }
    }
}

extern "C" void kernel_launch(void* const* d_in, const int* in_sizes, int n_in,
                              void* d_out, int out_size, void* d_ws, size_t ws_size,
                              hipStream_t stream) {
    const float* rgb    = (const float*)d_in[0];   // [B,R,S,3]
    const float* sigma  = (const float*)d_in[1];   // [B,R,S,1]
    const float* z_vals = (const float*)d_in[2];   // [B,R,S,1]

    const int n_rays = in_sizes[1] / NSAMP;        // B*R = 131072

    float* out         = (float*)d_out;
    float* rgb_out     = out;                              // n_rays*3
    float* depth_out   = out + (long long)n_rays * 3;      // n_rays
    float* weights_out = out + (long long)n_rays * 4;      // n_rays*64

    const int block = 256;                      // 4 waves/block
    const int rays_per_block = (block / 64) * IT;
    const int grid = (n_rays + rays_per_block - 1) / rays_per_block;  // 2048

    volrend_kernel<<<grid, block, 0, stream>>>(
        rgb, sigma, z_vals, rgb_out, depth_out, weights_out, n_rays);
}

// Round 4
// 200.505 us; speedup vs baseline: 1.0731x; 1.0731x over previous
//
#include <hip/hip_runtime.h>

// Volume rendering (NeRF-style fancy_integration), f32 in/out.
// B=4, R=32768, S=64 -> 131072 rays, 64 samples.
//
// Round 4 mapping: one wave = 4 rays. Each 16-lane DPP row owns one ray;
// each lane owns 4 consecutive samples (16B/lane vector loads).
//   sigma/z/weights: one float4 per lane, wave covers 1KiB contiguous.
//   rgb: three float4 per lane (48B = its own 4 samples' rgb), 3KiB/wave.
// All cross-lane traffic is 4-step DPP row_shr scans within each row.
// Rounds 1-3 showed VALU ~30%/HBM ~22%/LDS 0 with ~20 scalar loads per ray:
// memory-front-end request-rate bound, not pipe bound. This cuts load
// instructions per ray ~13x and puts 5KB/wave in flight.

#define EPS_W 1e-10f
#define DELTA_INF_V 1e10f

#define DPP_ROW_SHL(n) (0x100 | (n))
#define DPP_ROW_SHR(n) (0x110 | (n))

template <int CTRL>
__device__ __forceinline__ float dpp_mov(float x, float old) {
    return __builtin_bit_cast(float,
        __builtin_amdgcn_update_dpp(
            __builtin_bit_cast(int, old), __builtin_bit_cast(int, x),
            CTRL, 0xf, 0xf, false));
}

// Inclusive multiply-scan within each 16-lane row (identity 1.0).
__device__ __forceinline__ float row_scan_mul(float p) {
    p *= dpp_mov<DPP_ROW_SHR(1)>(p, 1.0f);
    p *= dpp_mov<DPP_ROW_SHR(2)>(p, 1.0f);
    p *= dpp_mov<DPP_ROW_SHR(4)>(p, 1.0f);
    p *= dpp_mov<DPP_ROW_SHR(8)>(p, 1.0f);
    return p;
}

// Row sum; lane 15 of each row ends with the full row total.
__device__ __forceinline__ float row_sum(float x) {
    x += dpp_mov<DPP_ROW_SHR(1)>(x, 0.0f);
    x += dpp_mov<DPP_ROW_SHR(2)>(x, 0.0f);
    x += dpp_mov<DPP_ROW_SHR(4)>(x, 0.0f);
    x += dpp_mov<DPP_ROW_SHR(8)>(x, 0.0f);
    return x;
}

__global__ __launch_bounds__(256) void volrend_kernel(
    const float* __restrict__ rgb,      // [n_rays, 64, 3]
    const float* __restrict__ sigma,    // [n_rays, 64]
    const float* __restrict__ z_vals,   // [n_rays, 64]
    float* __restrict__ rgb_out,        // [n_rays, 3]
    float* __restrict__ depth_out,      // [n_rays]
    float* __restrict__ weights_out,    // [n_rays, 64]
    int n_rays)
{
    const int lane = threadIdx.x & 63;
    const int wave = threadIdx.x >> 6;
    const long long wave_g = (long long)blockIdx.x * (blockDim.x >> 6) + wave;

    const int j   = lane & 15;   // lane within row: samples 4j..4j+3
    const int row = lane >> 4;   // ray within wave
    const long long ray = wave_g * 4 + row;
    if (ray >= n_rays) return;   // rows are independent; tail-safe

    // ---- vector loads: fully linear in lane ----
    const float4 sg = *(reinterpret_cast<const float4*>(sigma  + wave_g * 256) + lane);
    const float4 zz = *(reinterpret_cast<const float4*>(z_vals + wave_g * 256) + lane);
    const float4* rgb4 = reinterpret_cast<const float4*>(rgb + wave_g * 768 + (long long)lane * 12);
    const float4 c0 = rgb4[0];   // r0 g0 b0 r1
    const float4 c1 = rgb4[1];   // g1 b1 r2 g2
    const float4 c2 = rgb4[2];   // b2 r3 g3 b3

    // ---- deltas (z of next sample; cross-lane only for the 4th) ----
    const float zn = dpp_mov<DPP_ROW_SHL(1)>(zz.x, 0.0f);  // next lane's z0
    const float d0 = zz.y - zz.x;
    const float d1 = zz.z - zz.y;
    const float d2 = zz.w - zz.z;
    const float d3 = (j == 15) ? DELTA_INF_V : (zn - zz.w); // sample 63 -> inf

    // ---- alpha = 1 - exp(-delta * relu(sigma)) ----
    const float a0 = 1.0f - __expf(-d0 * fmaxf(sg.x, 0.0f));
    const float a1 = 1.0f - __expf(-d1 * fmaxf(sg.y, 0.0f));
    const float a2 = 1.0f - __expf(-d2 * fmaxf(sg.z, 0.0f));
    const float a3 = 1.0f - __expf(-d3 * fmaxf(sg.w, 0.0f));

    // ---- exclusive cumprod of (1 - a + eps): local scan x row scan ----
    const float q0 = 1.0f - a0 + EPS_W;
    const float q1 = 1.0f - a1 + EPS_W;
    const float q2 = 1.0f - a2 + EPS_W;
    const float q3 = 1.0f - a3 + EPS_W;
    const float P0 = q0;
    const float P1 = P0 * q1;
    const float P2 = P1 * q2;
    const float P3 = P2 * q3;

    const float R = row_scan_mul(P3);                  // inclusive over lanes
    const float E = dpp_mov<DPP_ROW_SHR(1)>(R, 1.0f);  // exclusive; lane0 = 1

    const float T0 = E;
    const float T1 = E * P0;
    const float T2 = E * P1;
    const float T3 = E * P2;

    const float w0 = a0 * T0;
    const float w1 = a1 * T1;
    const float w2 = a2 * T2;
    const float w3 = a3 * T3;

    // ---- weights: one contiguous float4 store per lane ----
    float4 wv; wv.x = w0; wv.y = w1; wv.z = w2; wv.w = w3;
    *(reinterpret_cast<float4*>(weights_out + wave_g * 256) + lane) = wv;

    // ---- weighted sums (rgb + depth), 4-step row reductions ----
    float pr = w0 * c0.x + w1 * c0.w + w2 * c1.z + w3 * c2.y;
    float pg = w0 * c0.y + w1 * c1.x + w2 * c1.w + w3 * c2.z;
    float pb = w0 * c0.z + w1 * c1.y + w2 * c2.x + w3 * c2.w;
    float pd = w0 * zz.x + w1 * zz.y + w2 * zz.z + w3 * zz.w;

    pr = row_sum(pr);
    pg = row_sum(pg);
    pb = row_sum(pb);
    pd = row_sum(pd);

    if (j == 15) {
        rgb_out[ray * 3 + 0] = pr;
        rgb_out[ray * 3 + 1] = pg;
        rgb_out[ray * 3 + 2] = pb;
        depth_out[ray] = pd;
    }
}

extern "C" void kernel_launch(void* const* d_in, const int* in_sizes, int n_in,
                              void* d_out, int out_size, void* d_ws, size_t ws_size,
                              hipStream_t stream) {
    const float* rgb    = (const float*)d_in[0];   // [B,R,S,3]
    const float* sigma  = (const float*)d_in[1];   // [B,R,S,1]
    const float* z_vals = (const float*)d_in[2];   // [B,R,S,1]

    const int n_rays = in_sizes[1] / 64;           // B*R = 131072

    float* out         = (float*)d_out;
    float* rgb_out     = out;                              // n_rays*3
    float* depth_out   = out + (long long)n_rays * 3;      // n_rays
    float* weights_out = out + (long long)n_rays * 4;      // n_rays*64

    const int block = 256;                      // 4 waves = 16 rays per block
    const int rays_per_block = (block / 64) * 4;
    const int grid = (n_rays + rays_per_block - 1) / rays_per_block;  // 8192

    volrend_kernel<<<grid, block, 0, stream>>>(
        rgb, sigma, z_vals, rgb_out, depth_out, weights_out, n_rays);
}

// Round 5
// 193.378 us; speedup vs baseline: 1.1126x; 1.0369x over previous
//
#include <hip/hip_runtime.h>

// Volume rendering (NeRF-style fancy_integration), f32 in/out.
// B=4, R=32768, S=64 -> 131072 rays, 64 samples.
//
// Round 5: R4 mapping unchanged (wave = 4 rays, 16-lane row per ray, 4
// samples per lane, all-float4 traffic, DPP row scans). Single change:
// ALL global accesses are non-temporal (`nt`). Evidence: R1-R4 pinned at
// ~70us with VALU 9%/HBM 21%/LDS 0 and ~7000cy wave lifetimes -> memory
// queueing. Outputs have zero in-kernel reuse and inputs are read once;
// nt keeps our 36MB of stores from evicting L3-resident input lines and
// from adding dirty-eviction churn on top of the harness restore drain.

#define EPS_W 1e-10f
#define DELTA_INF_V 1e10f

#define DPP_ROW_SHL(n) (0x100 | (n))
#define DPP_ROW_SHR(n) (0x110 | (n))

using f4 = __attribute__((ext_vector_type(4))) float;

template <int CTRL>
__device__ __forceinline__ float dpp_mov(float x, float old) {
    return __builtin_bit_cast(float,
        __builtin_amdgcn_update_dpp(
            __builtin_bit_cast(int, old), __builtin_bit_cast(int, x),
            CTRL, 0xf, 0xf, false));
}

// Inclusive multiply-scan within each 16-lane row (identity 1.0).
__device__ __forceinline__ float row_scan_mul(float p) {
    p *= dpp_mov<DPP_ROW_SHR(1)>(p, 1.0f);
    p *= dpp_mov<DPP_ROW_SHR(2)>(p, 1.0f);
    p *= dpp_mov<DPP_ROW_SHR(4)>(p, 1.0f);
    p *= dpp_mov<DPP_ROW_SHR(8)>(p, 1.0f);
    return p;
}

// Row sum; lane 15 of each row ends with the full row total.
__device__ __forceinline__ float row_sum(float x) {
    x += dpp_mov<DPP_ROW_SHR(1)>(x, 0.0f);
    x += dpp_mov<DPP_ROW_SHR(2)>(x, 0.0f);
    x += dpp_mov<DPP_ROW_SHR(4)>(x, 0.0f);
    x += dpp_mov<DPP_ROW_SHR(8)>(x, 0.0f);
    return x;
}

__global__ __launch_bounds__(256) void volrend_kernel(
    const float* __restrict__ rgb,      // [n_rays, 64, 3]
    const float* __restrict__ sigma,    // [n_rays, 64]
    const float* __restrict__ z_vals,   // [n_rays, 64]
    float* __restrict__ rgb_out,        // [n_rays, 3]
    float* __restrict__ depth_out,      // [n_rays]
    float* __restrict__ weights_out,    // [n_rays, 64]
    int n_rays)
{
    const int lane = threadIdx.x & 63;
    const int wave = threadIdx.x >> 6;
    const long long wave_g = (long long)blockIdx.x * (blockDim.x >> 6) + wave;

    const int j   = lane & 15;   // lane within row: samples 4j..4j+3
    const int row = lane >> 4;   // ray within wave
    const long long ray = wave_g * 4 + row;
    if (ray >= n_rays) return;

    // ---- non-temporal vector loads: fully linear in lane ----
    const f4 sg = __builtin_nontemporal_load(
        reinterpret_cast<const f4*>(sigma + wave_g * 256) + lane);
    const f4 zz = __builtin_nontemporal_load(
        reinterpret_cast<const f4*>(z_vals + wave_g * 256) + lane);
    const f4* rgb4 = reinterpret_cast<const f4*>(rgb + wave_g * 768 + (long long)lane * 12);
    const f4 c0 = __builtin_nontemporal_load(rgb4 + 0);   // r0 g0 b0 r1
    const f4 c1 = __builtin_nontemporal_load(rgb4 + 1);   // g1 b1 r2 g2
    const f4 c2 = __builtin_nontemporal_load(rgb4 + 2);   // b2 r3 g3 b3

    // ---- deltas ----
    const float zn = dpp_mov<DPP_ROW_SHL(1)>(zz.x, 0.0f);  // next lane's z0
    const float d0 = zz.y - zz.x;
    const float d1 = zz.z - zz.y;
    const float d2 = zz.w - zz.z;
    const float d3 = (j == 15) ? DELTA_INF_V : (zn - zz.w); // sample 63 -> inf

    // ---- alpha = 1 - exp(-delta * relu(sigma)) ----
    const float a0 = 1.0f - __expf(-d0 * fmaxf(sg.x, 0.0f));
    const float a1 = 1.0f - __expf(-d1 * fmaxf(sg.y, 0.0f));
    const float a2 = 1.0f - __expf(-d2 * fmaxf(sg.z, 0.0f));
    const float a3 = 1.0f - __expf(-d3 * fmaxf(sg.w, 0.0f));

    // ---- exclusive cumprod of (1 - a + eps): local scan x row scan ----
    const float q0 = 1.0f - a0 + EPS_W;
    const float q1 = 1.0f - a1 + EPS_W;
    const float q2 = 1.0f - a2 + EPS_W;
    const float q3 = 1.0f - a3 + EPS_W;
    const float P0 = q0;
    const float P1 = P0 * q1;
    const float P2 = P1 * q2;
    const float P3 = P2 * q3;

    const float R = row_scan_mul(P3);                  // inclusive over lanes
    const float E = dpp_mov<DPP_ROW_SHR(1)>(R, 1.0f);  // exclusive; lane0 = 1

    const float T0 = E;
    const float T1 = E * P0;
    const float T2 = E * P1;
    const float T3 = E * P2;

    const float w0 = a0 * T0;
    const float w1 = a1 * T1;
    const float w2 = a2 * T2;
    const float w3 = a3 * T3;

    // ---- weights: one contiguous nt float4 store per lane ----
    f4 wv; wv.x = w0; wv.y = w1; wv.z = w2; wv.w = w3;
    __builtin_nontemporal_store(
        wv, reinterpret_cast<f4*>(weights_out + wave_g * 256) + lane);

    // ---- weighted sums (rgb + depth), 4-step row reductions ----
    float pr = w0 * c0.x + w1 * c0.w + w2 * c1.z + w3 * c2.y;
    float pg = w0 * c0.y + w1 * c1.x + w2 * c1.w + w3 * c2.z;
    float pb = w0 * c0.z + w1 * c1.y + w2 * c2.x + w3 * c2.w;
    float pd = w0 * zz.x + w1 * zz.y + w2 * zz.z + w3 * zz.w;

    pr = row_sum(pr);
    pg = row_sum(pg);
    pb = row_sum(pb);
    pd = row_sum(pd);

    if (j == 15) {
        __builtin_nontemporal_store(pr, rgb_out + ray * 3 + 0);
        __builtin_nontemporal_store(pg, rgb_out + ray * 3 + 1);
        __builtin_nontemporal_store(pb, rgb_out + ray * 3 + 2);
        __builtin_nontemporal_store(pd, depth_out + ray);
    }
}

extern "C" void kernel_launch(void* const* d_in, const int* in_sizes, int n_in,
                              void* d_out, int out_size, void* d_ws, size_t ws_size,
                              hipStream_t stream) {
    const float* rgb    = (const float*)d_in[0];   // [B,R,S,3]
    const float* sigma  = (const float*)d_in[1];   // [B,R,S,1]
    const float* z_vals = (const float*)d_in[2];   // [B,R,S,1]

    const int n_rays = in_sizes[1] / 64;           // B*R = 131072

    float* out         = (float*)d_out;
    float* rgb_out     = out;                              // n_rays*3
    float* depth_out   = out + (long long)n_rays * 3;      // n_rays
    float* weights_out = out + (long long)n_rays * 4;      // n_rays*64

    const int block = 256;                      // 4 waves = 16 rays per block
    const int rays_per_block = (block / 64) * 4;
    const int grid = (n_rays + rays_per_block - 1) / rays_per_block;  // 8192

    volrend_kernel<<<grid, block, 0, stream>>>(
        rgb, sigma, z_vals, rgb_out, depth_out, weights_out, n_rays);
}